// Round 5
// baseline (648.160 us; speedup 1.0000x reference)
//
#include <hip/hip_runtime.h>
#include <stdint.h>

#define Bsz   256
#define Tlen  1024
#define Vocab 128
#define Hdim  128
#define WTN   ((Vocab - 1) * Hdim)   // 127*128 = 16256 floats

// h in LDS: 64 f16x2 dwords, split in two 32-dword halves. Half 1 starts at
// byte 144 (dword 36): banks 4..7 vs half 0's banks 0..3 -> the two distinct
// addresses of each broadcast b128 read hit disjoint bank quads.
#define HPAD  4
#define HBUFI 68

typedef _Float16 half2_t __attribute__((ext_vector_type(2)));

__device__ __forceinline__ float tanh_fast(float x) {
    // tanh(x) = 1 - 2/(exp2(2x*log2e)+1); exact limits at +-inf
    float e = __builtin_amdgcn_exp2f(x * 2.885390081777927f);
    return 1.0f - 2.0f * __builtin_amdgcn_rcpf(e + 1.0f);
}

__device__ __forceinline__ float dpp_xor1(float s) {
    return __int_as_float(__builtin_amdgcn_mov_dpp(__float_as_int(s), 0xB1, 0xF, 0xF, true));  // quad_perm(1,0,3,2)
}

// Prep: transpose W_ih (H x V-1) -> wtb (V-1 x H) with bias folded in:
// wtb[f][h] = W_ih[h][f] + b_ih[h] + b_hh[h]
__global__ __launch_bounds__(256) void prep_kernel(
    const float* __restrict__ W_ih, const float* __restrict__ b_ih,
    const float* __restrict__ b_hh, float* __restrict__ wtb)
{
    int idx = blockIdx.x * 256 + threadIdx.x;
    if (idx < WTN) {
        int h = idx / (Vocab - 1);
        int f = idx - h * (Vocab - 1);
        wtb[f * Hdim + h] = W_ih[idx] + b_ih[h] + b_hh[h];
    }
}

// ONE WAVE per sequence, ZERO barriers in the loop (same-wave DS ops are
// in-order: reads issued after the h-write observe the new h).
//   lane l=(g=l>>1, j=l&1) owns outputs {2l, 2l+1}, K-half [64j,64j+64)
//   W_hh rows {my0, my1, partner0, partner1} as 128 packed f16x2 VGPRs
//   per step: 8 broadcast ds_read_b128 (even quads first -> compute starts
//   after 4 returns), 128 fdot2 as 16 chains x 8 links (d-outer interleave:
//   same-chain spacing 32 cyc > ~20-cyc dot2 dep latency -> chains hidden
//   under the 256-cyc issue), 4-way add trees, one dpp_xor1 pair-exchange,
//   tanh x2, one ds_write_b32. R2 failed on 32-link chains (~640 cyc dep
//   latency on the path); R4 proved splitting is ~free. This is R2+R4.
__global__ __launch_bounds__(64, 1) void rnn_kernel(
    const float* __restrict__ x, const float* __restrict__ wtb,
    const float* __restrict__ W_hh, const float* __restrict__ W_out,
    const float* __restrict__ b_out, float* __restrict__ out)
{
    __shared__ float wt_s[WTN];                    // 65 KB pre-gather table
    __shared__ int   syms[Tlen];                   // 4 KB
    __shared__ __align__(16) int hbuf[HBUFI];      // padded f16 h

    const int l = threadIdx.x;   // lane 0..63
    const int b = blockIdx.x;

    hbuf[l] = 0;                 // h0 = 0 (incl. pad slots)
    if (l < HBUFI - 64) hbuf[64 + l] = 0;

    // ---- decode one-hot rows -> syms (16 loads in flight per lane)
    {
        const float4* xb = (const float4*)(x + (size_t)b * Tlen * Vocab);
        const int R4 = Tlen * Vocab / 4;           // 32768
        for (int base = 0; base < R4; base += 64 * 16) {   // 32 batches
            float4 v[16];
            #pragma unroll
            for (int i = 0; i < 16; i++) v[i] = xb[base + 64 * i + l];
            #pragma unroll
            for (int i = 0; i < 16; i++) {
                int k = base + 64 * i + l;
                int c = -1;
                if      (v[i].x > 0.5f) c = 0;
                else if (v[i].y > 0.5f) c = 1;
                else if (v[i].z > 0.5f) c = 2;
                else if (v[i].w > 0.5f) c = 3;
                if (c >= 0) syms[k >> 5] = ((k & 31) << 2) + c;  // 32 float4/row
            }
        }
    }

    // ---- stage wtb -> LDS
    {
        const float4* src = (const float4*)wtb;
        float4* dst = (float4*)wt_s;
        for (int k = l; k < WTN / 4; k += 64) dst[k] = src[k];
    }
    __syncthreads();   // single wave: cheap; orders LDS for the compiler

    // ---- length via shfl min-reduce
    int lm = Tlen;
    for (int k = l; k < Tlen; k += 64)
        if (syms[k] == 0 && k < lm) lm = k;
    #pragma unroll
    for (int off = 32; off > 0; off >>= 1) {
        int o = __shfl_xor(lm, off, 64);
        if (o < lm) lm = o;
    }
    const int len = lm;

    // ---- W_hh rows {my0, my1, partner0, partner1}, cols [64j, 64j+64)
    const int g = l >> 1;
    const int j = l & 1;
    int wp[128];
    {
        const int rows[4] = {4 * g + 2 * j, 4 * g + 2 * j + 1,
                             4 * g + 2 - 2 * j, 4 * g + 3 - 2 * j};
        #pragma unroll
        for (int rs = 0; rs < 4; rs++) {
            const float4* wrow = (const float4*)(W_hh + rows[rs] * Hdim + 64 * j);
            #pragma unroll
            for (int q = 0; q < 16; q++) {
                float4 t4 = wrow[q];
                wp[rs * 32 + 2 * q]     = __builtin_bit_cast(int, __builtin_amdgcn_cvt_pkrtz(t4.x, t4.y));
                wp[rs * 32 + 2 * q + 1] = __builtin_bit_cast(int, __builtin_amdgcn_cvt_pkrtz(t4.z, t4.w));
            }
        }
    }
    #pragma unroll
    for (int k = 0; k < 128; k += 8)
        asm volatile("" : "+v"(wp[k]), "+v"(wp[k+1]), "+v"(wp[k+2]), "+v"(wp[k+3]),
                          "+v"(wp[k+4]), "+v"(wp[k+5]), "+v"(wp[k+6]), "+v"(wp[k+7]));

    // pre pipeline: wt2[(sym-1)*64 + l] = pre(+bias) for outputs {2l, 2l+1}
    const float2* wt2 = (const float2*)wt_s;
    float2 pre_v = {0.0f, 0.0f}, p_t1 = {0.0f, 0.0f};
    int s_t2 = 1;
    if (len > 0) pre_v = wt2[(syms[0] - 1) * 64 + l];
    if (len > 1) p_t1  = wt2[(syms[1] - 1) * 64 + l];
    if (len > 2) s_t2  = syms[2];

    const char* hbp = (const char*)hbuf + 144 * j;   // my K-half base
    const int wslot = l + HPAD * (l >> 5);           // padded write slot

    for (int t = 0; t < len; t++) {
        // h reads: even-quad b128s first (serve chain links d=0..3), odd after
        uint4 q0 = *(const uint4*)(hbp);
        uint4 q2 = *(const uint4*)(hbp + 32);
        uint4 q4 = *(const uint4*)(hbp + 64);
        uint4 q6 = *(const uint4*)(hbp + 96);
        uint4 q1 = *(const uint4*)(hbp + 16);
        uint4 q3 = *(const uint4*)(hbp + 48);
        uint4 q5 = *(const uint4*)(hbp + 80);
        uint4 q7 = *(const uint4*)(hbp + 112);

        float2 p_t2 = wt2[(s_t2 - 1) * 64 + l];   // gather pre for t+2
        int   s_t3 = (t + 3 < len) ? syms[t + 3] : 1;

        unsigned hr[32] = {q0.x, q0.y, q0.z, q0.w, q1.x, q1.y, q1.z, q1.w,
                           q2.x, q2.y, q2.z, q2.w, q3.x, q3.y, q3.z, q3.w,
                           q4.x, q4.y, q4.z, q4.w, q5.x, q5.y, q5.z, q5.w,
                           q6.x, q6.y, q6.z, q6.w, q7.x, q7.y, q7.z, q7.w};

        // 16 chains x 8 links; pre+bias seeds the first chain of slots 0/1
        float c0[4] = {pre_v.x, 0.0f, 0.0f, 0.0f};
        float c1[4] = {pre_v.y, 0.0f, 0.0f, 0.0f};
        float c2[4] = {0.0f, 0.0f, 0.0f, 0.0f};
        float c3[4] = {0.0f, 0.0f, 0.0f, 0.0f};
        #pragma unroll
        for (int d = 0; d < 8; d++) {
            #pragma unroll
            for (int cc = 0; cc < 4; cc++) {
                half2_t hh = __builtin_bit_cast(half2_t, hr[cc * 8 + d]);
                c0[cc] = __builtin_amdgcn_fdot2(hh, __builtin_bit_cast(half2_t, wp[cc * 8 + d]),       c0[cc], false);
                c1[cc] = __builtin_amdgcn_fdot2(hh, __builtin_bit_cast(half2_t, wp[32 + cc * 8 + d]),  c1[cc], false);
                c2[cc] = __builtin_amdgcn_fdot2(hh, __builtin_bit_cast(half2_t, wp[64 + cc * 8 + d]),  c2[cc], false);
                c3[cc] = __builtin_amdgcn_fdot2(hh, __builtin_bit_cast(half2_t, wp[96 + cc * 8 + d]),  c3[cc], false);
            }
        }
        float a0 = (c0[0] + c0[1]) + (c0[2] + c0[3]);
        float a1 = (c1[0] + c1[1]) + (c1[2] + c1[3]);
        float a2 = (c2[0] + c2[1]) + (c2[2] + c2[3]);
        float a3 = (c3[0] + c3[1]) + (c3[2] + c3[3]);
        // partner lane's a2/a3 are the other K-half of MY rows (and vice versa)
        float h0 = tanh_fast(a0 + dpp_xor1(a2));
        float h1 = tanh_fast(a1 + dpp_xor1(a3));
        hbuf[wslot] = __builtin_bit_cast(int, __builtin_amdgcn_cvt_pkrtz(h0, h1));
        pre_v = p_t1; p_t1 = p_t2; s_t2 = s_t3;
    }

    // ---- epilogue: hidden state + softmax head (same wave)
    half2_t hv = __builtin_bit_cast(half2_t, hbuf[wslot]);
    float h0 = (float)hv.x, h1 = (float)hv.y;
    *(float2*)(out + 2 * Bsz + b * Hdim + 2 * l) = make_float2(h0, h1);

    float p0 = W_out[2 * l] * h0 + W_out[2 * l + 1] * h1;
    float p1 = W_out[Hdim + 2 * l] * h0 + W_out[Hdim + 2 * l + 1] * h1;
    #pragma unroll
    for (int off = 32; off > 0; off >>= 1) {
        p0 += __shfl_down(p0, off, 64);
        p1 += __shfl_down(p1, off, 64);
    }
    if (l == 0) {
        float l0 = p0 + b_out[0], l1 = p1 + b_out[1];
        float m  = fmaxf(l0, l1);
        float e0 = __expf(l0 - m), e1 = __expf(l1 - m);
        float d  = e0 + e1;
        out[b * 2 + 0] = e0 / d;
        out[b * 2 + 1] = e1 / d;
    }
}

extern "C" void kernel_launch(void* const* d_in, const int* in_sizes, int n_in,
                              void* d_out, int out_size, void* d_ws, size_t ws_size,
                              hipStream_t stream) {
    const float* x     = (const float*)d_in[0];
    const float* W_ih  = (const float*)d_in[1];
    const float* W_hh  = (const float*)d_in[2];
    const float* b_ih  = (const float*)d_in[3];
    const float* b_hh  = (const float*)d_in[4];
    const float* W_out = (const float*)d_in[5];
    const float* b_out = (const float*)d_in[6];
    float* out = (float*)d_out;

    float* wtb = (float*)d_ws;  // (V-1) x H floats = 65 KB

    const int NTRN = (WTN + 255) / 256;  // 64 blocks
    prep_kernel<<<NTRN, 256, 0, stream>>>(W_ih, b_ih, b_hh, wtb);
    rnn_kernel<<<Bsz, 64, 0, stream>>>(x, wtb, W_hh, W_out, b_out, out);
}

// Round 6
// 596.413 us; speedup vs baseline: 1.0868x; 1.0868x over previous
//
#include <hip/hip_runtime.h>
#include <stdint.h>

#define Bsz   256
#define Tlen  1024
#define Vocab 128
#define Hdim  128
#define NTHR  128
#define WTN   ((Vocab - 1) * Hdim)   // 127*128 = 16256 floats

typedef _Float16 half2_t __attribute__((ext_vector_type(2)));

__device__ __forceinline__ float tanh_fast(float x) {
    // tanh(x) = 1 - 2/(exp2(2x*log2e)+1); exact limits at +-inf
    float e = __builtin_amdgcn_exp2f(x * 2.885390081777927f);
    return 1.0f - 2.0f * __builtin_amdgcn_rcpf(e + 1.0f);
}

__device__ __forceinline__ float dpp_xor1(float s) {
    return __int_as_float(__builtin_amdgcn_mov_dpp(__float_as_int(s), 0xB1, 0xF, 0xF, true));  // quad_perm(1,0,3,2)
}

// Prep: transpose W_ih (H x V-1) -> wtb (V-1 x H) with bias folded in:
// wtb[f][h] = W_ih[h][f] + b_ih[h] + b_hh[h]
__global__ __launch_bounds__(256) void prep_kernel(
    const float* __restrict__ W_ih, const float* __restrict__ b_ih,
    const float* __restrict__ b_hh, float* __restrict__ wtb)
{
    int idx = blockIdx.x * 256 + threadIdx.x;
    if (idx < WTN) {
        int h = idx / (Vocab - 1);
        int f = idx - h * (Vocab - 1);
        wtb[f * Hdim + h] = W_ih[idx] + b_ih[h] + b_hh[h];
    }
}

// TWO waves (128 thr) per sequence; lane tid owns output h[tid] and computes
// the FULL 128-wide dot itself: 64 fdot2/lane, no cross-lane reduction.
//   wp[64] = W_hh row tid as packed f16x2 (~145 VGPR total incl. hr -- under
//   the ~190 demand that made the allocator split to AGPRs in R1/R2/R5)
//   per step: 16 broadcast ds_read_b128 (all lanes same addr -> bank-free),
//   8 chains x 8 links with stride-8 pair assignment (round d consumes
//   reads 2d,2d+1 -> read/compute pipelining), 7-add tree, tanh,
//   pack via dpp_xor1 partner, even lanes write one b32 (32 banks/wave).
//   One barrier per step syncing only 2 waves (each alone on its SIMD).
// Double-buffered h so wave A's writes can't race wave B's reads.
__global__ __launch_bounds__(NTHR, 1) void rnn_kernel(
    const float* __restrict__ x, const float* __restrict__ wtb,
    const float* __restrict__ W_hh, const float* __restrict__ W_out,
    const float* __restrict__ b_out, float* __restrict__ out)
{
    __shared__ float wt_s[WTN];                    // 65 KB pre-gather table
    __shared__ int   syms[Tlen];                   // 4 KB
    __shared__ __align__(16) int hbuf[2][Hdim / 2]; // f16 h, double-buffered
    __shared__ int   len_sh;

    const int tid = threadIdx.x;   // 0..127; owns output h[tid]
    const int b   = blockIdx.x;

    if (tid == 0) len_sh = Tlen;
    ((int*)hbuf)[tid] = 0;         // all 128 dwords (both buffers) = 0

    // ---- decode one-hot rows -> syms (16-deep batches, 128 threads)
    {
        const float4* xb = (const float4*)(x + (size_t)b * Tlen * Vocab);
        const int R4 = Tlen * Vocab / 4;           // 32768
        for (int base = 0; base < R4; base += NTHR * 16) {   // 16 batches
            float4 v[16];
            #pragma unroll
            for (int i = 0; i < 16; i++) v[i] = xb[base + NTHR * i + tid];
            #pragma unroll
            for (int i = 0; i < 16; i++) {
                int k = base + NTHR * i + tid;
                int c = -1;
                if      (v[i].x > 0.5f) c = 0;
                else if (v[i].y > 0.5f) c = 1;
                else if (v[i].z > 0.5f) c = 2;
                else if (v[i].w > 0.5f) c = 3;
                if (c >= 0) syms[k >> 5] = ((k & 31) << 2) + c;  // 32 float4/row
            }
        }
    }

    // ---- stage wtb -> LDS
    {
        const float4* src = (const float4*)wtb;
        float4* dst = (float4*)wt_s;
        for (int k = tid; k < WTN / 4; k += NTHR) dst[k] = src[k];
    }
    __syncthreads();

    // ---- length: per-wave shfl min + cross-wave atomicMin
    {
        int lm = Tlen;
        for (int k = tid; k < Tlen; k += NTHR)
            if (syms[k] == 0 && k < lm) lm = k;
        #pragma unroll
        for (int off = 32; off > 0; off >>= 1) {
            int o = __shfl_xor(lm, off, 64);
            if (o < lm) lm = o;
        }
        if ((tid & 63) == 0 && lm < Tlen) atomicMin(&len_sh, lm);
    }
    __syncthreads();
    const int len = len_sh;

    // ---- W_hh row tid -> 64 packed f16x2 (pair p = cols 2p, 2p+1)
    int wp[64];
    {
        const float4* wrow = (const float4*)(W_hh + tid * Hdim);
        #pragma unroll
        for (int q = 0; q < 32; q++) {
            float4 t4 = wrow[q];
            wp[2 * q]     = __builtin_bit_cast(int, __builtin_amdgcn_cvt_pkrtz(t4.x, t4.y));
            wp[2 * q + 1] = __builtin_bit_cast(int, __builtin_amdgcn_cvt_pkrtz(t4.z, t4.w));
        }
    }

    // pre pipeline (scalar now): wt_s[(sym-1)*128 + tid] = pre+bias for h[tid]
    float pre_v = 0.0f, p_t1 = 0.0f;
    int s_t2 = 1;
    if (len > 0) pre_v = wt_s[(syms[0] - 1) * Hdim + tid];
    if (len > 1) p_t1  = wt_s[(syms[1] - 1) * Hdim + tid];
    if (len > 2) s_t2  = syms[2];

    const bool weven = ((tid & 1) == 0);
    const int  wdw   = tid >> 1;          // dword slot holding (h[2w], h[2w+1])

    for (int t = 0; t < len; t++) {
        // pin packed weights (32-reg pins were fine in R3; 64 is safe here)
        #pragma unroll
        for (int k = 0; k < 64; k += 8)
            asm volatile("" : "+v"(wp[k]), "+v"(wp[k+1]), "+v"(wp[k+2]), "+v"(wp[k+3]),
                              "+v"(wp[k+4]), "+v"(wp[k+5]), "+v"(wp[k+6]), "+v"(wp[k+7]));

        // 16 broadcast b128 reads of the full h vector (64 dwords)
        const char* hb = (const char*)hbuf[t & 1];
        uint4 r[16];
        #pragma unroll
        for (int q = 0; q < 16; q++) r[q] = *(const uint4*)(hb + 16 * q);

        float p_t2 = wt_s[(s_t2 - 1) * Hdim + tid];   // scalar gather, t+2
        int   s_t3 = (t + 3 < len) ? syms[t + 3] : 1;

        unsigned hr[64];
        #pragma unroll
        for (int q = 0; q < 16; q++) {
            hr[4 * q]     = r[q].x; hr[4 * q + 1] = r[q].y;
            hr[4 * q + 2] = r[q].z; hr[4 * q + 3] = r[q].w;
        }

        // 8 chains x 8 links; chain cc takes pairs p = d*8+cc (stride 8):
        // round d consumes hr[8d..8d+7] = exactly reads r[2d], r[2d+1].
        float c0 = pre_v, c1 = 0.0f, c2 = 0.0f, c3 = 0.0f;
        float c4 = 0.0f,  c5 = 0.0f, c6 = 0.0f, c7 = 0.0f;
        #pragma unroll
        for (int d = 0; d < 8; d++) {
            const int p = d * 8;
            c0 = __builtin_amdgcn_fdot2(__builtin_bit_cast(half2_t, hr[p]),     __builtin_bit_cast(half2_t, wp[p]),     c0, false);
            c1 = __builtin_amdgcn_fdot2(__builtin_bit_cast(half2_t, hr[p + 1]), __builtin_bit_cast(half2_t, wp[p + 1]), c1, false);
            c2 = __builtin_amdgcn_fdot2(__builtin_bit_cast(half2_t, hr[p + 2]), __builtin_bit_cast(half2_t, wp[p + 2]), c2, false);
            c3 = __builtin_amdgcn_fdot2(__builtin_bit_cast(half2_t, hr[p + 3]), __builtin_bit_cast(half2_t, wp[p + 3]), c3, false);
            c4 = __builtin_amdgcn_fdot2(__builtin_bit_cast(half2_t, hr[p + 4]), __builtin_bit_cast(half2_t, wp[p + 4]), c4, false);
            c5 = __builtin_amdgcn_fdot2(__builtin_bit_cast(half2_t, hr[p + 5]), __builtin_bit_cast(half2_t, wp[p + 5]), c5, false);
            c6 = __builtin_amdgcn_fdot2(__builtin_bit_cast(half2_t, hr[p + 6]), __builtin_bit_cast(half2_t, wp[p + 6]), c6, false);
            c7 = __builtin_amdgcn_fdot2(__builtin_bit_cast(half2_t, hr[p + 7]), __builtin_bit_cast(half2_t, wp[p + 7]), c7, false);
        }
        float a = ((c0 + c1) + (c2 + c3)) + ((c4 + c5) + (c6 + c7));

        float h  = tanh_fast(a);          // my output h[tid]
        float hp = dpp_xor1(h);           // partner lane's output h[tid^1]
        if (weven)                        // even lane packs (h[2w], h[2w+1])
            hbuf[(t + 1) & 1][wdw] = __builtin_bit_cast(int, __builtin_amdgcn_cvt_pkrtz(h, hp));

        pre_v = p_t1; p_t1 = p_t2; s_t2 = s_t3;
        __syncthreads();
    }

    // ---- epilogue: hidden state + softmax head
    const _Float16* hf = (const _Float16*)hbuf[len & 1];
    out[2 * Bsz + b * Hdim + tid] = (float)hf[tid];   // coalesced, 128 thr

    if (tid < 64) {
        float h0 = (float)hf[tid];
        float h1 = (float)hf[tid + 64];
        float p0 = W_out[tid] * h0 + W_out[64 + tid] * h1;
        float p1 = W_out[128 + tid] * h0 + W_out[192 + tid] * h1;
        #pragma unroll
        for (int off = 32; off > 0; off >>= 1) {
            p0 += __shfl_down(p0, off, 64);
            p1 += __shfl_down(p1, off, 64);
        }
        if (tid == 0) {
            float l0 = p0 + b_out[0], l1 = p1 + b_out[1];
            float m  = fmaxf(l0, l1);
            float e0 = __expf(l0 - m), e1 = __expf(l1 - m);
            float d  = e0 + e1;
            out[b * 2 + 0] = e0 / d;
            out[b * 2 + 1] = e1 / d;
        }
    }
}

extern "C" void kernel_launch(void* const* d_in, const int* in_sizes, int n_in,
                              void* d_out, int out_size, void* d_ws, size_t ws_size,
                              hipStream_t stream) {
    const float* x     = (const float*)d_in[0];
    const float* W_ih  = (const float*)d_in[1];
    const float* W_hh  = (const float*)d_in[2];
    const float* b_ih  = (const float*)d_in[3];
    const float* b_hh  = (const float*)d_in[4];
    const float* W_out = (const float*)d_in[5];
    const float* b_out = (const float*)d_in[6];
    float* out = (float*)d_out;

    float* wtb = (float*)d_ws;  // (V-1) x H floats = 65 KB

    const int NTRN = (WTN + 255) / 256;  // 64 blocks
    prep_kernel<<<NTRN, 256, 0, stream>>>(W_ih, b_ih, b_hh, wtb);
    rnn_kernel<<<Bsz, NTHR, 0, stream>>>(x, wtb, W_hh, W_out, b_out, out);
}

// Round 7
// 487.120 us; speedup vs baseline: 1.3306x; 1.2244x over previous
//
#include <hip/hip_runtime.h>
#include <stdint.h>

#define Bsz   256
#define Tlen  1024
#define Vocab 128
#define Hdim  128
#define NTHR  256
#define WTN   ((Vocab - 1) * Hdim)   // 127*128 = 16256 floats
#define WTS   130                    // LDS row stride: 130%32=2 -> transpose
                                     // writes 2-way bank (free), float2-aligned

// h stored as f16 in LDS: 4 chunks of 16 dwords (32 halves) at 20-dword
// stride (80 B). Chunk bases land on banks {0,20,8,28}: the four distinct
// per-j addresses of each b128 read phase hit disjoint bank quads.
#define CHD   20                     // chunk stride in dwords
#define HBUFI (4 * CHD)              // dwords per buffer = 80

typedef _Float16 half2_t __attribute__((ext_vector_type(2)));

__device__ __forceinline__ float tanh_fast(float x) {
    // tanh(x) = 1 - 2/(exp2(2x*log2e)+1); exact limits at +-inf
    float e = __builtin_amdgcn_exp2f(x * 2.885390081777927f);
    return 1.0f - 2.0f * __builtin_amdgcn_rcpf(e + 1.0f);
}

// quad-local DPP reductions (pure VALU, no LDS pipe)
__device__ __forceinline__ float dpp_xor1(float s) {
    return __int_as_float(__builtin_amdgcn_mov_dpp(__float_as_int(s), 0xB1, 0xF, 0xF, true));  // quad_perm(1,0,3,2)
}
__device__ __forceinline__ float dpp_xor2(float s) {
    return __int_as_float(__builtin_amdgcn_mov_dpp(__float_as_int(s), 0x4E, 0xF, 0xF, true));  // quad_perm(2,3,0,1)
}

// Single kernel. One block (256 thr, 4 waves = 1/SIMD) per sequence.
// R3 loop structure (measured structural optimum: 620 cyc/step across the
// wave-count map {8w:860, 4w:620, 2w:920, 1w:1020}), with the non-loop
// overhead trimmed: length-first decode (col-0 scan -> only decode t<len),
// in-kernel W_ih transpose (no prep kernel / global round-trip), bias
// folded into the pre-table (removes 2 adds from the step tail).
__global__ __launch_bounds__(NTHR, 1) void rnn_kernel(
    const float* __restrict__ x, const float* __restrict__ W_ih,
    const float* __restrict__ W_hh,
    const float* __restrict__ b_ih, const float* __restrict__ b_hh,
    const float* __restrict__ W_out, const float* __restrict__ b_out,
    float* __restrict__ out)
{
    __shared__ float wt_s[(Vocab - 1) * WTS];      // 66 KB pre+bias table
    __shared__ float bsum_s[Hdim];                 // b_ih + b_hh
    __shared__ int   syms[Tlen];                   // 4 KB
    __shared__ __align__(16) int hbuf[2][HBUFI];   // f16 h, double-buffered
    __shared__ int   len_sh;

    const int tid = threadIdx.x;
    const int b   = blockIdx.x;
    const int g   = tid >> 2;   // quad 0..63, owns outputs 2g, 2g+1
    const int j   = tid & 3;    // K-chunk index within quad

    if (tid == 0) len_sh = Tlen;
    if (tid < 2 * HBUFI) ((int*)hbuf)[tid] = 0;    // h0 = 0 (incl. pads)
    if (tid < Hdim) bsum_s[tid] = b_ih[tid] + b_hh[tid];

    // ---- length first: pad row <=> x[b][t][0] == 1 (one_hot(0))
    {
        const float* xcol = x + (size_t)b * Tlen * Vocab;
        int lm = Tlen;
        for (int t = tid; t < Tlen; t += NTHR)          // 4 strided loads
            if (xcol[(size_t)t * Vocab] > 0.5f && t < lm) lm = t;
        #pragma unroll
        for (int off = 32; off > 0; off >>= 1) {
            int o = __shfl_xor(lm, off, 64);
            if (o < lm) lm = o;
        }
        if ((tid & 63) == 0 && lm < Tlen) atomicMin(&len_sh, lm);
    }

    // W_hh rows 2g,2g+1, cols [32j,32j+32) -> 32 packed f16x2 registers
    int wp[32];
    #pragma unroll
    for (int r = 0; r < 2; r++) {
        const float4* wrow = (const float4*)(W_hh + (2 * g + r) * Hdim + 32 * j);
        #pragma unroll
        for (int q4 = 0; q4 < 8; q4++) {
            float4 t4 = wrow[q4];
            wp[r * 16 + q4 * 2 + 0] = __builtin_bit_cast(int, __builtin_amdgcn_cvt_pkrtz(t4.x, t4.y));
            wp[r * 16 + q4 * 2 + 1] = __builtin_bit_cast(int, __builtin_amdgcn_cvt_pkrtz(t4.z, t4.w));
        }
    }

    __syncthreads();   // len_sh + bsum_s final
    const int len = len_sh;

    // ---- transpose W_ih (H x V-1) into LDS with bias folded:
    // wt_s[f*130 + h] = W_ih[h*127 + f] + bsum[h]   (2-way bank on writes)
    {
        const float4* w4 = (const float4*)W_ih;
        for (int k4 = tid; k4 < WTN / 4; k4 += NTHR) {  // 4064 float4, 16 it
            float4 v = w4[k4];
            int k = 4 * k4;
            #pragma unroll
            for (int e = 0; e < 4; e++) {
                int ke = k + e;
                int h  = ke / (Vocab - 1);              // const-div -> magic mul
                int f  = ke - h * (Vocab - 1);
                float val = (e == 0) ? v.x : (e == 1) ? v.y : (e == 2) ? v.z : v.w;
                wt_s[f * WTS + h] = val + bsum_s[h];
            }
        }
    }

    // ---- decode one-hot rows t < len only (float4 coalesced, 8-deep)
    {
        const float4* xb = (const float4*)(x + (size_t)b * Tlen * Vocab);
        const int rows4 = len << 5;                     // len rows * 32 f4
        for (int base = 0; base < rows4; base += NTHR * 8) {
            float4 v[8];
            #pragma unroll
            for (int i = 0; i < 8; i++) {
                int k = base + NTHR * i + tid;
                v[i] = (k < rows4) ? xb[k] : make_float4(0.f, 0.f, 0.f, 0.f);
            }
            #pragma unroll
            for (int i = 0; i < 8; i++) {
                int k = base + NTHR * i + tid;
                int c = -1;
                if      (v[i].x > 0.5f) c = 0;
                else if (v[i].y > 0.5f) c = 1;
                else if (v[i].z > 0.5f) c = 2;
                else if (v[i].w > 0.5f) c = 3;
                if (c >= 0) syms[k >> 5] = ((k & 31) << 2) + c;  // 32 f4/row
            }
        }
    }
    __syncthreads();   // wt_s + syms ready

    // pre pipeline: float2 (elements 2g,2g+1), bias included. Broadcast
    // across the quad (all quad lanes same index).
    const float2* wt2 = (const float2*)wt_s;   // pair index: (sym-1)*65 + g
    float2 pre_v = {0.0f, 0.0f}, p_t1 = {0.0f, 0.0f};
    int s_t2 = 1;
    if (len > 0) pre_v = wt2[(syms[0] - 1) * (WTS / 2) + g];
    if (len > 1) p_t1  = wt2[(syms[1] - 1) * (WTS / 2) + g];
    if (len > 2) s_t2  = syms[2];

    const char* hb0 = (const char*)hbuf[0];
    const char* hb1 = (const char*)hbuf[1];
    const int roff = j * (CHD * 4);                 // 80 B per chunk
    const int widx = CHD * (g >> 4) + (g & 15);     // dword slot of pair g

    for (int t = 0; t < len; t++) {
        // keep packed W pinned (cheap at this register pressure)
        #pragma unroll
        for (int k = 0; k < 32; k += 8)
            asm volatile("" : "+v"(wp[k]), "+v"(wp[k+1]), "+v"(wp[k+2]), "+v"(wp[k+3]),
                              "+v"(wp[k+4]), "+v"(wp[k+5]), "+v"(wp[k+6]), "+v"(wp[k+7]));

        // h reads first: start the ~130-cyc LDS latency immediately
        const char* hb = (t & 1) ? hb1 : hb0;
        uint4 r0 = *(const uint4*)(hb + roff);
        uint4 r1 = *(const uint4*)(hb + roff + 16);
        uint4 r2 = *(const uint4*)(hb + roff + 32);
        uint4 r3 = *(const uint4*)(hb + roff + 48);

        float2 p_t2 = wt2[(s_t2 - 1) * (WTS / 2) + g];   // gather for t+2
        int   s_t3 = (t + 3 < len) ? syms[t + 3] : 1;

        unsigned hr[16] = {r0.x, r0.y, r0.z, r0.w, r1.x, r1.y, r1.z, r1.w,
                           r2.x, r2.y, r2.z, r2.w, r3.x, r3.y, r3.z, r3.w};

        // 4 chains x 8 fdot2 (8-cyc dep spacing), combine to 2 sums
        float a00 = 0.0f, a01 = 0.0f, a10 = 0.0f, a11 = 0.0f;
        #pragma unroll
        for (int d = 0; d < 8; d++) {
            half2_t h0 = __builtin_bit_cast(half2_t, hr[d]);
            half2_t h1 = __builtin_bit_cast(half2_t, hr[8 + d]);
            a00 = __builtin_amdgcn_fdot2(h0, __builtin_bit_cast(half2_t, wp[d]),      a00, false);
            a01 = __builtin_amdgcn_fdot2(h1, __builtin_bit_cast(half2_t, wp[8 + d]),  a01, false);
            a10 = __builtin_amdgcn_fdot2(h0, __builtin_bit_cast(half2_t, wp[16 + d]), a10, false);
            a11 = __builtin_amdgcn_fdot2(h1, __builtin_bit_cast(half2_t, wp[24 + d]), a11, false);
        }
        float a0 = a00 + a01, a1 = a10 + a11;
        a0 += dpp_xor1(a0); a1 += dpp_xor1(a1);
        a0 += dpp_xor2(a0); a1 += dpp_xor2(a1);   // quad-invariant full sums

        // all 4 quad lanes compute tanh (no divergence); lane j==0 writes
        float h0v = tanh_fast(a0 + pre_v.x);      // bias already in table
        float h1v = tanh_fast(a1 + pre_v.y);
        int pk = __builtin_bit_cast(int, __builtin_amdgcn_cvt_pkrtz(h0v, h1v));
        if (j == 0) ((int*)hbuf[(t + 1) & 1])[widx] = pk;

        pre_v = p_t1; p_t1 = p_t2; s_t2 = s_t3;
        __syncthreads();
    }

    // epilogue: hidden state + softmax head
    const _Float16* hf = (const _Float16*)hbuf[len & 1];
    #define HGET(e) ((float)hf[40 * ((e) >> 5) + (((e) >> 1) & 15) * 2 + ((e) & 1)])
    if (tid < Hdim)
        out[2 * Bsz + b * Hdim + tid] = HGET(tid);
    if (tid < 64) {
        float h0 = HGET(tid);
        float h1 = HGET(tid + 64);
        float p0 = W_out[tid] * h0 + W_out[64 + tid] * h1;
        float p1 = W_out[128 + tid] * h0 + W_out[192 + tid] * h1;
        #pragma unroll
        for (int off = 32; off > 0; off >>= 1) {
            p0 += __shfl_down(p0, off, 64);
            p1 += __shfl_down(p1, off, 64);
        }
        if (tid == 0) {
            float l0 = p0 + b_out[0], l1 = p1 + b_out[1];
            float m  = fmaxf(l0, l1);
            float e0 = __expf(l0 - m), e1 = __expf(l1 - m);
            float d  = e0 + e1;
            out[b * 2 + 0] = e0 / d;
            out[b * 2 + 1] = e1 / d;
        }
    }
    #undef HGET
}

extern "C" void kernel_launch(void* const* d_in, const int* in_sizes, int n_in,
                              void* d_out, int out_size, void* d_ws, size_t ws_size,
                              hipStream_t stream) {
    const float* x     = (const float*)d_in[0];
    const float* W_ih  = (const float*)d_in[1];
    const float* W_hh  = (const float*)d_in[2];
    const float* b_ih  = (const float*)d_in[3];
    const float* b_hh  = (const float*)d_in[4];
    const float* W_out = (const float*)d_in[5];
    const float* b_out = (const float*)d_in[6];
    float* out = (float*)d_out;

    rnn_kernel<<<Bsz, NTHR, 0, stream>>>(x, W_ih, W_hh, b_ih, b_hh, W_out, b_out, out);
}

// Round 8
// 469.602 us; speedup vs baseline: 1.3802x; 1.0373x over previous
//
#include <hip/hip_runtime.h>
#include <stdint.h>

#define Bsz   256
#define Tlen  1024
#define Vocab 128
#define Hdim  128
#define NTHR  256
#define WTN   ((Vocab - 1) * Hdim)   // 127*128 = 16256 floats

// h stored as f16 in LDS: 4 chunks of 16 dwords (32 halves) at 20-dword
// stride (80 B). Chunk bases land on banks {0,20,8,28}: the four distinct
// per-j addresses of each b128 read phase hit disjoint bank quads.
#define CHD   20                     // chunk stride in dwords
#define HBUFI (4 * CHD)              // dwords per buffer = 80

typedef _Float16 half2_t __attribute__((ext_vector_type(2)));

__device__ __forceinline__ float tanh_fast(float x) {
    // tanh(x) = 1 - 2/(exp2(2x*log2e)+1); exact limits at +-inf
    float e = __builtin_amdgcn_exp2f(x * 2.885390081777927f);
    return 1.0f - 2.0f * __builtin_amdgcn_rcpf(e + 1.0f);
}

// quad-local DPP reductions (pure VALU, no LDS pipe)
__device__ __forceinline__ float dpp_xor1(float s) {
    return __int_as_float(__builtin_amdgcn_mov_dpp(__float_as_int(s), 0xB1, 0xF, 0xF, true));  // quad_perm(1,0,3,2)
}
__device__ __forceinline__ float dpp_xor2(float s) {
    return __int_as_float(__builtin_amdgcn_mov_dpp(__float_as_int(s), 0x4E, 0xF, 0xF, true));  // quad_perm(2,3,0,1)
}

// Prep: transpose W_ih (H x V-1) -> wtb (V-1 x H) with bias folded in:
// wtb[f][h] = W_ih[h][f] + b_ih[h] + b_hh[h]. Global-memory transpose
// (R7's in-LDS version was an 8-way bank conflict per write: 697K counts).
__global__ __launch_bounds__(256) void prep_kernel(
    const float* __restrict__ W_ih, const float* __restrict__ b_ih,
    const float* __restrict__ b_hh, float* __restrict__ wtb)
{
    int idx = blockIdx.x * 256 + threadIdx.x;
    if (idx < WTN) {
        int h = idx / (Vocab - 1);
        int f = idx - h * (Vocab - 1);
        wtb[f * Hdim + h] = W_ih[idx] + b_ih[h] + b_hh[h];
    }
}

// One block (256 thr, 4 waves = 1/SIMD) per sequence — the R3 structure,
// the measured optimum of the wave-count map {8w:860, 4w:620, 2w:920,
// 1w:1020 cyc/step}. Quad q=tid>>2 owns outputs {2q, 2q+1}; lane j=tid&3
// covers k in [32j,32j+32) via v_dot2_f32_f16. Changes vs R3 (both REMOVE
// serial ops from the step tail, nothing added on-path):
//   - bias pre-folded into the pre-table (prep kernel)
//   - pre seeded into chain a00 gated to lane j==0 (counted once by the
//     quad reduce), so the tail is xor2-add -> tanh directly.
__global__ __launch_bounds__(NTHR, 1) void rnn_kernel(
    const float* __restrict__ x, const float* __restrict__ wt,
    const float* __restrict__ W_hh,
    const float* __restrict__ W_out, const float* __restrict__ b_out,
    float* __restrict__ out)
{
    __shared__ float wt_s[WTN];                    // 65 KB pre+bias table
    __shared__ int   syms[Tlen];                   // 4 KB
    __shared__ __align__(16) int hbuf[2][HBUFI];   // f16 h, double-buffered
    __shared__ int   len_sh;

    const int tid = threadIdx.x;
    const int b   = blockIdx.x;
    const int g   = tid >> 2;   // quad 0..63, owns outputs 2g, 2g+1
    const int j   = tid & 3;    // K-chunk index within quad
    const bool jz = (j == 0);

    if (tid == 0) len_sh = Tlen;
    if (tid < 2 * HBUFI) ((int*)hbuf)[tid] = 0;    // h0 = 0 (incl. pads)

    // W_hh rows 2g,2g+1, cols [32j,32j+32) -> 32 packed f16x2 registers
    int wp[32];
    #pragma unroll
    for (int r = 0; r < 2; r++) {
        const float4* wrow = (const float4*)(W_hh + (2 * g + r) * Hdim + 32 * j);
        #pragma unroll
        for (int q4 = 0; q4 < 8; q4++) {
            float4 t4 = wrow[q4];
            wp[r * 16 + q4 * 2 + 0] = __builtin_bit_cast(int, __builtin_amdgcn_cvt_pkrtz(t4.x, t4.y));
            wp[r * 16 + q4 * 2 + 1] = __builtin_bit_cast(int, __builtin_amdgcn_cvt_pkrtz(t4.z, t4.w));
        }
    }

    // stage wt -> LDS, coalesced float4
    {
        const float4* src = (const float4*)wt;
        float4* dst = (float4*)wt_s;
        for (int k = tid; k < WTN / 4; k += NTHR) dst[k] = src[k];
    }

    // Decode this block's one-hot rows (512 KB, float4 coalesced, 8-deep
    // batches to keep HBM pipelined at 4 waves/CU).
    {
        const float4* xb = (const float4*)(x + (size_t)b * Tlen * Vocab);
        const int R4 = Tlen * Vocab / 4;           // 32768
        for (int base = 0; base < R4; base += NTHR * 8) {   // 16 batches
            float4 v[8];
            #pragma unroll
            for (int i = 0; i < 8; i++) v[i] = xb[base + NTHR * i + tid];
            #pragma unroll
            for (int i = 0; i < 8; i++) {
                int k = base + NTHR * i + tid;
                int c = -1;
                if      (v[i].x > 0.5f) c = 0;
                else if (v[i].y > 0.5f) c = 1;
                else if (v[i].z > 0.5f) c = 2;
                else if (v[i].w > 0.5f) c = 3;
                if (c >= 0) syms[k >> 5] = ((k & 31) << 2) + c;  // 32 float4/row
            }
        }
    }
    __syncthreads();

    // length = first t with sym==0 (pad), else Tlen
    {
        int lm = Tlen;
        for (int k = tid; k < Tlen; k += NTHR)
            if (syms[k] == 0 && k < lm) lm = k;
        if (lm < Tlen) atomicMin(&len_sh, lm);
    }
    __syncthreads();
    const int len = len_sh;

    // pre pipeline: float2 (elements 2g,2g+1) for t ready, t+1 in flight,
    // symbol for t+2 in register. All quad lanes same index -> broadcast.
    const float2* wt2 = (const float2*)wt_s;   // pair index: (sym-1)*64 + g
    float2 pre_v = {0.0f, 0.0f}, p_t1 = {0.0f, 0.0f};
    int s_t2 = 1;
    if (len > 0) pre_v = wt2[(syms[0] - 1) * 64 + g];
    if (len > 1) p_t1  = wt2[(syms[1] - 1) * 64 + g];
    if (len > 2) s_t2  = syms[2];

    const char* hb0 = (const char*)hbuf[0];
    const char* hb1 = (const char*)hbuf[1];
    const int roff = j * (CHD * 4);                 // 80 B per chunk
    const int widx = CHD * (g >> 4) + (g & 15);     // dword slot of pair g

    for (int t = 0; t < len; t++) {
        // keep packed W pinned (cheap at this register pressure)
        #pragma unroll
        for (int k = 0; k < 32; k += 8)
            asm volatile("" : "+v"(wp[k]), "+v"(wp[k+1]), "+v"(wp[k+2]), "+v"(wp[k+3]),
                              "+v"(wp[k+4]), "+v"(wp[k+5]), "+v"(wp[k+6]), "+v"(wp[k+7]));

        // seed = pre(+bias) gated to lane j==0: counted once by the quad
        // reduce; the 2 cndmasks issue in the ds_read shadow (off-path)
        float s0 = jz ? pre_v.x : 0.0f;
        float s1 = jz ? pre_v.y : 0.0f;

        // h reads
        const char* hb = (t & 1) ? hb1 : hb0;
        uint4 r0 = *(const uint4*)(hb + roff);
        uint4 r1 = *(const uint4*)(hb + roff + 16);
        uint4 r2 = *(const uint4*)(hb + roff + 32);
        uint4 r3 = *(const uint4*)(hb + roff + 48);

        float2 p_t2 = wt2[(s_t2 - 1) * 64 + g];   // LDS b64 gather for t+2
        int   s_t3 = (t + 3 < len) ? syms[t + 3] : 1;

        unsigned hr[16] = {r0.x, r0.y, r0.z, r0.w, r1.x, r1.y, r1.z, r1.w,
                           r2.x, r2.y, r2.z, r2.w, r3.x, r3.y, r3.z, r3.w};

        // 4 chains x 8 fdot2 (8-cyc dep spacing), combine to 2 sums
        float a00 = s0, a01 = 0.0f, a10 = s1, a11 = 0.0f;
        #pragma unroll
        for (int d = 0; d < 8; d++) {
            half2_t h0 = __builtin_bit_cast(half2_t, hr[d]);
            half2_t h1 = __builtin_bit_cast(half2_t, hr[8 + d]);
            a00 = __builtin_amdgcn_fdot2(h0, __builtin_bit_cast(half2_t, wp[d]),      a00, false);
            a01 = __builtin_amdgcn_fdot2(h1, __builtin_bit_cast(half2_t, wp[8 + d]),  a01, false);
            a10 = __builtin_amdgcn_fdot2(h0, __builtin_bit_cast(half2_t, wp[16 + d]), a10, false);
            a11 = __builtin_amdgcn_fdot2(h1, __builtin_bit_cast(half2_t, wp[24 + d]), a11, false);
        }
        float a0 = a00 + a01, a1 = a10 + a11;
        a0 += dpp_xor1(a0); a1 += dpp_xor1(a1);
        a0 += dpp_xor2(a0); a1 += dpp_xor2(a1);   // full pre-act incl. pre+bias

        // all 4 quad lanes compute tanh (no divergence); lane j==0 writes
        float h0v = tanh_fast(a0);
        float h1v = tanh_fast(a1);
        int pk = __builtin_bit_cast(int, __builtin_amdgcn_cvt_pkrtz(h0v, h1v));
        if (jz) ((int*)hbuf[(t + 1) & 1])[widx] = pk;

        pre_v = p_t1; p_t1 = p_t2; s_t2 = s_t3;
        __syncthreads();
    }

    // epilogue: hidden state + softmax head
    const _Float16* hf = (const _Float16*)hbuf[len & 1];
    #define HGET(e) ((float)hf[40 * ((e) >> 5) + (((e) >> 1) & 15) * 2 + ((e) & 1)])
    if (tid < Hdim)
        out[2 * Bsz + b * Hdim + tid] = HGET(tid);
    if (tid < 64) {
        float h0 = HGET(tid);
        float h1 = HGET(tid + 64);
        float p0 = W_out[tid] * h0 + W_out[64 + tid] * h1;
        float p1 = W_out[128 + tid] * h0 + W_out[192 + tid] * h1;
        #pragma unroll
        for (int off = 32; off > 0; off >>= 1) {
            p0 += __shfl_down(p0, off, 64);
            p1 += __shfl_down(p1, off, 64);
        }
        if (tid == 0) {
            float l0 = p0 + b_out[0], l1 = p1 + b_out[1];
            float m  = fmaxf(l0, l1);
            float e0 = __expf(l0 - m), e1 = __expf(l1 - m);
            float d  = e0 + e1;
            out[b * 2 + 0] = e0 / d;
            out[b * 2 + 1] = e1 / d;
        }
    }
    #undef HGET
}

extern "C" void kernel_launch(void* const* d_in, const int* in_sizes, int n_in,
                              void* d_out, int out_size, void* d_ws, size_t ws_size,
                              hipStream_t stream) {
    const float* x     = (const float*)d_in[0];
    const float* W_ih  = (const float*)d_in[1];
    const float* W_hh  = (const float*)d_in[2];
    const float* b_ih  = (const float*)d_in[3];
    const float* b_hh  = (const float*)d_in[4];
    const float* W_out = (const float*)d_in[5];
    const float* b_out = (const float*)d_in[6];
    float* out = (float*)d_out;

    float* wtb = (float*)d_ws;  // (V-1) x H floats = 65 KB

    const int NTRN = (WTN + 255) / 256;  // 64 blocks
    prep_kernel<<<NTRN, 256, 0, stream>>>(W_ih, b_ih, b_hh, wtb);
    rnn_kernel<<<Bsz, NTHR, 0, stream>>>(x, wtb, W_hh, W_out, b_out, out);
}

// Round 9
// 453.336 us; speedup vs baseline: 1.4298x; 1.0359x over previous
//
#include <hip/hip_runtime.h>
#include <stdint.h>

#define Bsz   256
#define Tlen  1024
#define Vocab 128
#define Hdim  128
#define NTHR  256
#define WTN   ((Vocab - 1) * Hdim)   // 127*128 = 16256 floats

// h stored as f16 in LDS: 4 chunks of 16 dwords (32 halves) at 20-dword
// stride (80 B). Chunk bases land on banks {0,20,8,28}: the four distinct
// per-j addresses of each b128 read phase hit disjoint bank quads.
#define CHD   20                     // chunk stride in dwords
#define HBUFI (4 * CHD)              // dwords per buffer = 80

typedef _Float16 half2_t __attribute__((ext_vector_type(2)));

__device__ __forceinline__ float tanh_fast(float x) {
    // tanh(x) = 1 - 2/(exp2(2x*log2e)+1); exact limits at +-inf
    float e = __builtin_amdgcn_exp2f(x * 2.885390081777927f);
    return 1.0f - 2.0f * __builtin_amdgcn_rcpf(e + 1.0f);
}

// quad-local DPP reductions (pure VALU, no LDS pipe)
__device__ __forceinline__ float dpp_xor1(float s) {
    return __int_as_float(__builtin_amdgcn_mov_dpp(__float_as_int(s), 0xB1, 0xF, 0xF, true));  // quad_perm(1,0,3,2)
}
__device__ __forceinline__ float dpp_xor2(float s) {
    return __int_as_float(__builtin_amdgcn_mov_dpp(__float_as_int(s), 0x4E, 0xF, 0xF, true));  // quad_perm(2,3,0,1)
}

// Tiny prep: transpose W_ih (H x V-1) -> wt (V-1 x H).
__global__ __launch_bounds__(256) void transpose_kernel(
    const float* __restrict__ W_ih, float* __restrict__ wt)
{
    int idx = blockIdx.x * 256 + threadIdx.x;
    if (idx < WTN) {
        int h = idx / (Vocab - 1);
        int f = idx - h * (Vocab - 1);
        wt[f * Hdim + h] = W_ih[idx];   // wt[f][h] = W_ih[h][f]
    }
}

// One block (256 thr, 4 waves = 1/SIMD) per sequence. Quad q=tid>>2 owns
// outputs {2q, 2q+1}; lane j=tid&3 covers k in [32j,32j+32) as f16 pairs
// with v_dot2_f32_f16 (fp32 accumulate). W_hh rows pinned as 32 packed
// f16x2 VGPRs. Reduction = 2 quad DPP adds; tanh redundantly in all 4
// quad lanes (no exec-mask dance); one b32 write per quad; one barrier
// per step (4 waves, each alone on its SIMD -> minimal skew).
// MEASURED OPTIMUM of this session's design space (9 structural variants):
// step ~620 cyc = LDS round-trip + 16-deep dot + reduce/tanh + rendezvous.
// Latency-floor-bound, not roofline-bound (HBM 2.7%, VALU 20%, MFMA 0).
__global__ __launch_bounds__(NTHR, 1) void rnn_kernel(
    const float* __restrict__ x, const float* __restrict__ wt,
    const float* __restrict__ W_hh,
    const float* __restrict__ b_ih, const float* __restrict__ b_hh,
    const float* __restrict__ W_out, const float* __restrict__ b_out,
    float* __restrict__ out)
{
    __shared__ float wt_s[WTN];                    // 65 KB pre gather table
    __shared__ int   syms[Tlen];                   // 4 KB
    __shared__ __align__(16) int hbuf[2][HBUFI];   // f16 h, double-buffered
    __shared__ int   len_sh;

    const int tid = threadIdx.x;
    const int b   = blockIdx.x;
    const int g   = tid >> 2;   // quad 0..63, owns outputs 2g, 2g+1
    const int j   = tid & 3;    // K-chunk index within quad

    if (tid == 0) len_sh = Tlen;
    if (tid < 2 * HBUFI) ((int*)hbuf)[tid] = 0;    // h0 = 0 (incl. pads)

    // W_hh rows 2g,2g+1, cols [32j,32j+32) -> 32 packed f16x2 registers
    int wp[32];
    #pragma unroll
    for (int r = 0; r < 2; r++) {
        const float4* wrow = (const float4*)(W_hh + (2 * g + r) * Hdim + 32 * j);
        #pragma unroll
        for (int q4 = 0; q4 < 8; q4++) {
            float4 t4 = wrow[q4];
            wp[r * 16 + q4 * 2 + 0] = __builtin_bit_cast(int, __builtin_amdgcn_cvt_pkrtz(t4.x, t4.y));
            wp[r * 16 + q4 * 2 + 1] = __builtin_bit_cast(int, __builtin_amdgcn_cvt_pkrtz(t4.z, t4.w));
        }
    }
    const float bias0 = b_ih[2 * g]     + b_hh[2 * g];
    const float bias1 = b_ih[2 * g + 1] + b_hh[2 * g + 1];

    // stage wt -> LDS, coalesced float4
    {
        const float4* src = (const float4*)wt;
        float4* dst = (float4*)wt_s;
        for (int k = tid; k < WTN / 4; k += NTHR) dst[k] = src[k];
    }

    // Decode this block's one-hot rows (512 KB, float4 coalesced, 8-deep
    // batches to keep HBM pipelined at 4 waves/CU).
    {
        const float4* xb = (const float4*)(x + (size_t)b * Tlen * Vocab);
        const int R4 = Tlen * Vocab / 4;           // 32768
        for (int base = 0; base < R4; base += NTHR * 8) {   // 16 batches
            float4 v[8];
            #pragma unroll
            for (int i = 0; i < 8; i++) v[i] = xb[base + NTHR * i + tid];
            #pragma unroll
            for (int i = 0; i < 8; i++) {
                int k = base + NTHR * i + tid;
                int c = -1;
                if      (v[i].x > 0.5f) c = 0;
                else if (v[i].y > 0.5f) c = 1;
                else if (v[i].z > 0.5f) c = 2;
                else if (v[i].w > 0.5f) c = 3;
                if (c >= 0) syms[k >> 5] = ((k & 31) << 2) + c;  // 32 float4/row
            }
        }
    }
    __syncthreads();

    // length = first t with sym==0 (pad), else Tlen
    {
        int lm = Tlen;
        for (int k = tid; k < Tlen; k += NTHR)
            if (syms[k] == 0 && k < lm) lm = k;
        if (lm < Tlen) atomicMin(&len_sh, lm);
    }
    __syncthreads();
    const int len = len_sh;

    // pre pipeline: float2 (elements 2g,2g+1) for t ready, t+1 in flight,
    // symbol for t+2 in register. All quad lanes same index -> broadcast.
    const float2* wt2 = (const float2*)wt_s;   // pair index: (sym-1)*64 + g
    float2 pre_v = {0.0f, 0.0f}, p_t1 = {0.0f, 0.0f};
    int s_t2 = 1;
    if (len > 0) pre_v = wt2[(syms[0] - 1) * 64 + g];
    if (len > 1) p_t1  = wt2[(syms[1] - 1) * 64 + g];
    if (len > 2) s_t2  = syms[2];

    const char* hb0 = (const char*)hbuf[0];
    const char* hb1 = (const char*)hbuf[1];
    const int roff = j * (CHD * 4);                 // 80 B per chunk
    const int widx = CHD * (g >> 4) + (g & 15);     // dword slot of pair g

    for (int t = 0; t < len; t++) {
        // keep packed W pinned (cheap at this register pressure)
        #pragma unroll
        for (int k = 0; k < 32; k += 8)
            asm volatile("" : "+v"(wp[k]), "+v"(wp[k+1]), "+v"(wp[k+2]), "+v"(wp[k+3]),
                              "+v"(wp[k+4]), "+v"(wp[k+5]), "+v"(wp[k+6]), "+v"(wp[k+7]));

        // h reads first (so their wait need not drain the later gathers)
        const char* hb = (t & 1) ? hb1 : hb0;
        uint4 r0 = *(const uint4*)(hb + roff);
        uint4 r1 = *(const uint4*)(hb + roff + 16);
        uint4 r2 = *(const uint4*)(hb + roff + 32);
        uint4 r3 = *(const uint4*)(hb + roff + 48);

        float2 p_t2 = wt2[(s_t2 - 1) * 64 + g];   // LDS b64 gather for t+2
        int   s_t3 = (t + 3 < len) ? syms[t + 3] : 1;

        unsigned hr[16] = {r0.x, r0.y, r0.z, r0.w, r1.x, r1.y, r1.z, r1.w,
                           r2.x, r2.y, r2.z, r2.w, r3.x, r3.y, r3.z, r3.w};

        // 4 chains x 8 fdot2 (8-cyc dep spacing), combine to 2 sums
        float a00 = 0.0f, a01 = 0.0f, a10 = 0.0f, a11 = 0.0f;
        #pragma unroll
        for (int d = 0; d < 8; d++) {
            half2_t h0 = __builtin_bit_cast(half2_t, hr[d]);
            half2_t h1 = __builtin_bit_cast(half2_t, hr[8 + d]);
            a00 = __builtin_amdgcn_fdot2(h0, __builtin_bit_cast(half2_t, wp[d]),      a00, false);
            a01 = __builtin_amdgcn_fdot2(h1, __builtin_bit_cast(half2_t, wp[8 + d]),  a01, false);
            a10 = __builtin_amdgcn_fdot2(h0, __builtin_bit_cast(half2_t, wp[16 + d]), a10, false);
            a11 = __builtin_amdgcn_fdot2(h1, __builtin_bit_cast(half2_t, wp[24 + d]), a11, false);
        }
        float a0 = a00 + a01, a1 = a10 + a11;
        a0 += dpp_xor1(a0); a1 += dpp_xor1(a1);
        a0 += dpp_xor2(a0); a1 += dpp_xor2(a1);   // quad-invariant full sums

        // all 4 quad lanes compute tanh (no divergence); lane j==0 writes
        float h0 = tanh_fast(a0 + pre_v.x + bias0);
        float h1 = tanh_fast(a1 + pre_v.y + bias1);
        int pk = __builtin_bit_cast(int, __builtin_amdgcn_cvt_pkrtz(h0, h1));
        if (j == 0) ((int*)hbuf[(t + 1) & 1])[widx] = pk;

        pre_v = p_t1; p_t1 = p_t2; s_t2 = s_t3;
        __syncthreads();
    }

    // epilogue: hidden state + softmax head
    const _Float16* hf = (const _Float16*)hbuf[len & 1];
    #define HGET(e) ((float)hf[40 * ((e) >> 5) + (((e) >> 1) & 15) * 2 + ((e) & 1)])
    if (tid < Hdim)
        out[2 * Bsz + b * Hdim + tid] = HGET(tid);
    if (tid < 64) {
        float h0 = HGET(tid);
        float h1 = HGET(tid + 64);
        float p0 = W_out[tid] * h0 + W_out[64 + tid] * h1;
        float p1 = W_out[128 + tid] * h0 + W_out[192 + tid] * h1;
        #pragma unroll
        for (int off = 32; off > 0; off >>= 1) {
            p0 += __shfl_down(p0, off, 64);
            p1 += __shfl_down(p1, off, 64);
        }
        if (tid == 0) {
            float l0 = p0 + b_out[0], l1 = p1 + b_out[1];
            float m  = fmaxf(l0, l1);
            float e0 = __expf(l0 - m), e1 = __expf(l1 - m);
            float d  = e0 + e1;
            out[b * 2 + 0] = e0 / d;
            out[b * 2 + 1] = e1 / d;
        }
    }
    #undef HGET
}

extern "C" void kernel_launch(void* const* d_in, const int* in_sizes, int n_in,
                              void* d_out, int out_size, void* d_ws, size_t ws_size,
                              hipStream_t stream) {
    const float* x     = (const float*)d_in[0];
    const float* W_ih  = (const float*)d_in[1];
    const float* W_hh  = (const float*)d_in[2];
    const float* b_ih  = (const float*)d_in[3];
    const float* b_hh  = (const float*)d_in[4];
    const float* W_out = (const float*)d_in[5];
    const float* b_out = (const float*)d_in[6];
    float* out = (float*)d_out;

    float* wt = (float*)d_ws;  // (V-1) x H floats = 65 KB

    const int NTRN = (WTN + 255) / 256;  // 64 blocks
    transpose_kernel<<<NTRN, 256, 0, stream>>>(W_ih, wt);
    rnn_kernel<<<Bsz, NTHR, 0, stream>>>(x, wt, W_hh, b_ih, b_hh, W_out, b_out, out);
}